// Round 1
// baseline (2768.252 us; speedup 1.0000x reference)
//
#include <hip/hip_runtime.h>

// Problem constants (SpatialAttention): B=32, C=512, D=64, H=W=32, N=1024
#define BB 32
#define CC 512
#define DD 64
#define NN 1024

typedef float4 f4;

// ---------------- out_w transpose: ow[co][c] -> owT[c][co] ----------------
__global__ __launch_bounds__(256) void transpose_ow_kernel(const float* __restrict__ ow,
                                                           float* __restrict__ owT) {
  int idx = blockIdx.x * 256 + threadIdx.x;   // 0 .. 512*512-1
  int co = idx >> 9;
  int c  = idx & 511;
  owT[c * 512 + co] = ow[idx];                // coalesced read, strided write (1 MB total, one-shot)
}

// ---------------- fused QKV projection ----------------
// Per batch: Y[i][o] = sum_c (x[b][c][i] + pos[c][i]) * W[o][c] + bias[o]
// o in [0,64) -> q[b][i][o], [64,128) -> k[b][i][o-64], [128,640) -> v[b][i][o-128]
__global__ __launch_bounds__(256) void proj_kernel(
    const float* __restrict__ x, const float* __restrict__ pos,
    const float* __restrict__ qw, const float* __restrict__ qb,
    const float* __restrict__ kw, const float* __restrict__ kb,
    const float* __restrict__ vw, const float* __restrict__ vb,
    float* __restrict__ q, float* __restrict__ k, float* __restrict__ v) {
  __shared__ float sA[16][68];   // [kk][mm]  (k x i tile), +4 pad
  __shared__ float sB[16][68];   // [kk][nn]  (k x o tile)

  const int m0 = blockIdx.x * 64;   // i tile
  const int n0 = blockIdx.y * 64;   // o tile (640 total -> 10 tiles)
  const int b  = blockIdx.z;
  const int tid = threadIdx.x;

  const float* wbase; const float* bbase; float* obase; int ostride;
  if (n0 < 64) {
    wbase = qw + n0 * 512;         bbase = qb + n0;
    obase = q + (size_t)b * NN * DD + n0;        ostride = DD;
  } else if (n0 < 128) {
    wbase = kw + (n0 - 64) * 512;  bbase = kb + (n0 - 64);
    obase = k + (size_t)b * NN * DD + (n0 - 64); ostride = DD;
  } else {
    wbase = vw + (n0 - 128) * 512; bbase = vb + (n0 - 128);
    obase = v + (size_t)b * NN * CC + (n0 - 128); ostride = CC;
  }

  const float* xb = x + (size_t)b * CC * NN;

  const int lkk  = tid >> 4;          // 0..15 A-load row (k)
  const int lmm  = (tid & 15) * 4;    // A-load col (i)
  const int lnn  = tid >> 2;          // 0..63 B-load row (o)
  const int lkk4 = (tid & 3) * 4;     // B-load col (k)

  const int mm = (tid >> 4) * 4;      // 0..60
  const int nn = (tid & 15) * 4;      // 0..60

  float acc[4][4] = {};

  for (int k0 = 0; k0 < 512; k0 += 16) {
    f4 xa = *(const f4*)(xb  + (size_t)(k0 + lkk) * NN + m0 + lmm);
    f4 pa = *(const f4*)(pos + (size_t)(k0 + lkk) * NN + m0 + lmm);
    sA[lkk][lmm + 0] = xa.x + pa.x;
    sA[lkk][lmm + 1] = xa.y + pa.y;
    sA[lkk][lmm + 2] = xa.z + pa.z;
    sA[lkk][lmm + 3] = xa.w + pa.w;
    f4 wv = *(const f4*)(wbase + (size_t)lnn * 512 + k0 + lkk4);
    sB[lkk4 + 0][lnn] = wv.x;
    sB[lkk4 + 1][lnn] = wv.y;
    sB[lkk4 + 2][lnn] = wv.z;
    sB[lkk4 + 3][lnn] = wv.w;
    __syncthreads();
#pragma unroll
    for (int kk = 0; kk < 16; ++kk) {
      float a0 = sA[kk][mm + 0], a1 = sA[kk][mm + 1], a2 = sA[kk][mm + 2], a3 = sA[kk][mm + 3];
      float b0 = sB[kk][nn + 0], b1 = sB[kk][nn + 1], b2 = sB[kk][nn + 2], b3 = sB[kk][nn + 3];
      acc[0][0] = fmaf(a0, b0, acc[0][0]); acc[0][1] = fmaf(a0, b1, acc[0][1]);
      acc[0][2] = fmaf(a0, b2, acc[0][2]); acc[0][3] = fmaf(a0, b3, acc[0][3]);
      acc[1][0] = fmaf(a1, b0, acc[1][0]); acc[1][1] = fmaf(a1, b1, acc[1][1]);
      acc[1][2] = fmaf(a1, b2, acc[1][2]); acc[1][3] = fmaf(a1, b3, acc[1][3]);
      acc[2][0] = fmaf(a2, b0, acc[2][0]); acc[2][1] = fmaf(a2, b1, acc[2][1]);
      acc[2][2] = fmaf(a2, b2, acc[2][2]); acc[2][3] = fmaf(a2, b3, acc[2][3]);
      acc[3][0] = fmaf(a3, b0, acc[3][0]); acc[3][1] = fmaf(a3, b1, acc[3][1]);
      acc[3][2] = fmaf(a3, b2, acc[3][2]); acc[3][3] = fmaf(a3, b3, acc[3][3]);
    }
    __syncthreads();
  }

  float bias0 = bbase[nn + 0], bias1 = bbase[nn + 1], bias2 = bbase[nn + 2], bias3 = bbase[nn + 3];
#pragma unroll
  for (int i = 0; i < 4; ++i) {
    f4 r;
    r.x = acc[i][0] + bias0;
    r.y = acc[i][1] + bias1;
    r.z = acc[i][2] + bias2;
    r.w = acc[i][3] + bias3;
    *(f4*)(obase + (size_t)(m0 + mm + i) * ostride + nn) = r;
  }
}

// ---------------- fused attention + output projection ----------------
// One block: batch b, query rows i0..i0+7.
__global__ __launch_bounds__(256) void attn_kernel(
    const float* __restrict__ q, const float* __restrict__ k,
    const float* __restrict__ v, const float* __restrict__ owT,
    const float* __restrict__ ob, float* __restrict__ out) {
  __shared__ float qs[8][64];       // 2 KB
  __shared__ float sp[8][1024];     // 32 KB  scores -> p
  __shared__ float osh[8][512];     // 16 KB  normalized attention output
  __shared__ float rinv[8];

  const int b   = blockIdx.y;
  const int i0  = blockIdx.x * 8;
  const int tid = threadIdx.x;

  // load 8 q rows (contiguous [i][d])
  for (int idx = tid; idx < 512; idx += 256) {
    qs[idx >> 6][idx & 63] = q[(size_t)b * NN * DD + (size_t)(i0 + (idx >> 6)) * DD + (idx & 63)];
  }
  __syncthreads();

  // scores: s[r][j] = dot64(q_r, k_j)
  const float* kb_ = k + (size_t)b * NN * DD;
  for (int j = tid; j < NN; j += 256) {
    const f4* kr = (const f4*)(kb_ + (size_t)j * DD);
    float acc[8] = {};
#pragma unroll
    for (int t = 0; t < 16; ++t) {
      f4 kv = kr[t];
#pragma unroll
      for (int r = 0; r < 8; ++r) {
        acc[r] = fmaf(kv.x, qs[r][4 * t + 0], acc[r]);
        acc[r] = fmaf(kv.y, qs[r][4 * t + 1], acc[r]);
        acc[r] = fmaf(kv.z, qs[r][4 * t + 2], acc[r]);
        acc[r] = fmaf(kv.w, qs[r][4 * t + 3], acc[r]);
      }
    }
#pragma unroll
    for (int r = 0; r < 8; ++r) sp[r][j] = acc[r];
  }
  __syncthreads();

  // softmax per row: wave w handles rows w and w+4
  const int wid = tid >> 6, lane = tid & 63;
  for (int r = wid; r < 8; r += 4) {
    float m = -1e30f;
    for (int j = lane; j < NN; j += 64) m = fmaxf(m, sp[r][j]);
#pragma unroll
    for (int off = 32; off > 0; off >>= 1) m = fmaxf(m, __shfl_xor(m, off, 64));
    float l = 0.f;
    for (int j = lane; j < NN; j += 64) {
      float p = __expf(sp[r][j] - m);
      sp[r][j] = p;
      l += p;
    }
#pragma unroll
    for (int off = 32; off > 0; off >>= 1) l += __shfl_xor(l, off, 64);
    if (lane == 0) rinv[r] = 1.0f / l;
  }
  __syncthreads();

  // attn . v : thread owns channels c0=tid, c1=tid+256
  const float* vb_ = v + (size_t)b * NN * CC;
  const int c0 = tid, c1 = tid + 256;
  float o0[8] = {}, o1[8] = {};
  for (int j = 0; j < NN; j += 4) {
    f4 p[8];
#pragma unroll
    for (int r = 0; r < 8; ++r) p[r] = *(const f4*)&sp[r][j];
#pragma unroll
    for (int jj = 0; jj < 4; ++jj) {
      float va = vb_[(size_t)(j + jj) * CC + c0];
      float vb2 = vb_[(size_t)(j + jj) * CC + c1];
#pragma unroll
      for (int r = 0; r < 8; ++r) {
        float pv = ((const float*)&p[r])[jj];
        o0[r] = fmaf(pv, va, o0[r]);
        o1[r] = fmaf(pv, vb2, o1[r]);
      }
    }
  }
#pragma unroll
  for (int r = 0; r < 8; ++r) {
    osh[r][c0] = o0[r] * rinv[r];
    osh[r][c1] = o1[r] * rinv[r];
  }
  __syncthreads();

  // fused output projection: y[r][co] = sum_c owT[c][co] * osh[r][c] + ob[co]
  float y0[8] = {}, y1[8] = {};
  for (int c = 0; c < 512; c += 4) {
    f4 oh[8];
#pragma unroll
    for (int r = 0; r < 8; ++r) oh[r] = *(const f4*)&osh[r][c];
#pragma unroll
    for (int cc = 0; cc < 4; ++cc) {
      float w0 = owT[(size_t)(c + cc) * 512 + c0];
      float w1 = owT[(size_t)(c + cc) * 512 + c1];
#pragma unroll
      for (int r = 0; r < 8; ++r) {
        float ov = ((const float*)&oh[r])[cc];
        y0[r] = fmaf(ov, w0, y0[r]);
        y1[r] = fmaf(ov, w1, y1[r]);
      }
    }
  }
  float bo0 = ob[c0], bo1 = ob[c1];
  float* p0 = out + (size_t)b * CC * NN + (size_t)c0 * NN + i0;
  float* p1 = out + (size_t)b * CC * NN + (size_t)c1 * NN + i0;
  f4 w;
  w.x = y0[0] + bo0; w.y = y0[1] + bo0; w.z = y0[2] + bo0; w.w = y0[3] + bo0;
  *(f4*)(p0 + 0) = w;
  w.x = y0[4] + bo0; w.y = y0[5] + bo0; w.z = y0[6] + bo0; w.w = y0[7] + bo0;
  *(f4*)(p0 + 4) = w;
  w.x = y1[0] + bo1; w.y = y1[1] + bo1; w.z = y1[2] + bo1; w.w = y1[3] + bo1;
  *(f4*)(p1 + 0) = w;
  w.x = y1[4] + bo1; w.y = y1[5] + bo1; w.z = y1[6] + bo1; w.w = y1[7] + bo1;
  *(f4*)(p1 + 4) = w;
}

extern "C" void kernel_launch(void* const* d_in, const int* in_sizes, int n_in,
                              void* d_out, int out_size, void* d_ws, size_t ws_size,
                              hipStream_t stream) {
  const float* x   = (const float*)d_in[0];
  const float* pos = (const float*)d_in[1];
  const float* qw  = (const float*)d_in[2];
  const float* qb  = (const float*)d_in[3];
  const float* kw  = (const float*)d_in[4];
  const float* kb  = (const float*)d_in[5];
  const float* vw  = (const float*)d_in[6];
  const float* vb  = (const float*)d_in[7];
  const float* ow  = (const float*)d_in[8];
  const float* ob  = (const float*)d_in[9];
  float* out = (float*)d_out;

  // workspace layout (floats): q[2M] k[2M] v[16M] owT[256K]  => ~81 MB
  float* ws  = (float*)d_ws;
  float* q   = ws;
  float* k   = q + (size_t)BB * NN * DD;
  float* v   = k + (size_t)BB * NN * DD;
  float* owT = v + (size_t)BB * NN * CC;

  hipLaunchKernelGGL(transpose_ow_kernel, dim3(1024), dim3(256), 0, stream, ow, owT);
  hipLaunchKernelGGL(proj_kernel, dim3(16, 10, 32), dim3(256), 0, stream,
                     x, pos, qw, qb, kw, kb, vw, vb, q, k, v);
  hipLaunchKernelGGL(attn_kernel, dim3(128, 32), dim3(256), 0, stream,
                     q, k, v, owT, ob, out);
}

// Round 3
// 382.292 us; speedup vs baseline: 7.2412x; 7.2412x over previous
//
#include <hip/hip_runtime.h>

// SpatialAttention: B=32, C=512, D=64, N=1024 (H=W=32)
#define BB 32
#define CC 512
#define DD 64
#define NN 1024
#define GRP 8                 // batches per attention group
#define NGRP (BB / GRP)       // 4 groups

typedef float4 f4;
typedef __attribute__((ext_vector_type(8))) short bf16x8;     // 8 bf16 = 4 VGPRs (MFMA A/B frag)
typedef __attribute__((ext_vector_type(4))) float f32x4;      // MFMA C/D frag
typedef __attribute__((ext_vector_type(4))) unsigned short us4;
typedef __attribute__((ext_vector_type(8))) unsigned short us8;

__device__ inline unsigned short bf16rn(float f) {
  union { float f; unsigned u; } v; v.f = f;
  unsigned r = v.u + 0x7fff + ((v.u >> 16) & 1);   // round-to-nearest-even
  return (unsigned short)(r >> 16);
}

__device__ inline void gl_lds16(const void* g, void* l) {
  // async global->LDS, 16B/lane; LDS dest = wave-uniform base + lane*16
  __builtin_amdgcn_global_load_lds(
      (const __attribute__((address_space(1))) unsigned int*)g,
      (__attribute__((address_space(3))) unsigned int*)l, 16, 0, 0);
}

// ---- shared GEMM core: C[128m x 128n] += A[M][K] * Bt[N][K]^T, bf16, BK=32 ----
// LDS tiles sA/sB are 128 rows x 32 cols bf16 row-major (64 B/row).
template <int KDIM>
__device__ inline void gemm_core(const unsigned short* __restrict__ A,
                                 const unsigned short* __restrict__ Bt,
                                 int m0, int n0, int tid,
                                 unsigned short* sA, unsigned short* sB,
                                 f32x4 acc[4][4]) {
  const int wave = tid >> 6, lane = tid & 63;
  const int lrow = lane >> 2;          // 0..15 within a wave's 16-row slab
  const int lcg  = (lane & 3) * 8;     // k element offset of this lane's 8 bf16
  const int wm = (wave & 1) * 64, wn = (wave >> 1) * 64;
  const int fm = lane & 15;            // fragment row (m or n)
  const int fk = (lane >> 4) * 8;      // fragment k offset

  for (int k0 = 0; k0 < KDIM; k0 += 32) {
#pragma unroll
    for (int qq = 0; qq < 2; ++qq) {
      gl_lds16(A  + (size_t)(m0 + wave * 16 + qq * 64 + lrow) * KDIM + k0 + lcg,
               sA + wave * 512 + qq * 2048);
      gl_lds16(Bt + (size_t)(n0 + wave * 16 + qq * 64 + lrow) * KDIM + k0 + lcg,
               sB + wave * 512 + qq * 2048);
    }
    __syncthreads();   // drains vmcnt (global_load_lds) for all waves
    bf16x8 af[4], bf[4];
#pragma unroll
    for (int i = 0; i < 4; ++i) {
      af[i] = *(const bf16x8*)(sA + (wm + i * 16 + fm) * 32 + fk);
      bf[i] = *(const bf16x8*)(sB + (wn + i * 16 + fm) * 32 + fk);
    }
#pragma unroll
    for (int i = 0; i < 4; ++i)
#pragma unroll
      for (int j = 0; j < 4; ++j)
        acc[i][j] = __builtin_amdgcn_mfma_f32_16x16x32_bf16(af[i], bf[j], acc[i][j], 0, 0, 0);
    __syncthreads();
  }
}

// ---------------- prep: weights -> bf16 ----------------
__global__ __launch_bounds__(256) void prep_w(
    const float* __restrict__ qw, const float* __restrict__ kw, const float* __restrict__ vw,
    const float* __restrict__ qb, const float* __restrict__ kb, const float* __restrict__ vb,
    const float* __restrict__ ow,
    unsigned short* __restrict__ wcat, unsigned short* __restrict__ owb,
    float* __restrict__ bcat) {
  int idx = blockIdx.x * 256 + threadIdx.x;   // 0 .. 640*512 + 512*512 - 1
  if (idx < 640 * 512) {
    int row = idx >> 9;
    float v = (row < 64) ? qw[idx] : (row < 128) ? kw[idx - 64 * 512] : vw[idx - 128 * 512];
    wcat[idx] = bf16rn(v);
    if (idx < 640) bcat[idx] = (idx < 64) ? qb[idx] : (idx < 128) ? kb[idx - 64] : vb[idx - 128];
  } else {
    int j = idx - 640 * 512;
    owb[j] = bf16rn(ow[j]);
  }
}

// ---------------- prep: A[b][i][c] = bf16(x[b][c][i] + pos[c][i]) ----------------
__global__ __launch_bounds__(256) void prep_x(const float* __restrict__ x,
                                              const float* __restrict__ pos,
                                              unsigned short* __restrict__ A) {
  __shared__ float t[64][65];
  const int b = blockIdx.z, i0 = blockIdx.x * 64, c0 = blockIdx.y * 64;
  const int tid = threadIdx.x;
  const int ci = tid >> 4, il = (tid & 15) * 4;
  const float* xb = x + (size_t)b * CC * NN;
#pragma unroll
  for (int r = 0; r < 4; ++r) {
    int cl = r * 16 + ci;
    f4 xv = *(const f4*)(xb  + (size_t)(c0 + cl) * NN + i0 + il);
    f4 pv = *(const f4*)(pos + (size_t)(c0 + cl) * NN + i0 + il);
    t[cl][il + 0] = xv.x + pv.x;
    t[cl][il + 1] = xv.y + pv.y;
    t[cl][il + 2] = xv.z + pv.z;
    t[cl][il + 3] = xv.w + pv.w;
  }
  __syncthreads();
  const int iw = tid >> 2, cw = (tid & 3) * 16;
  unsigned short* dst = A + ((size_t)b * NN + i0 + iw) * CC + c0 + cw;
  us8 p0, p1;
#pragma unroll
  for (int j = 0; j < 8; ++j) p0[j] = bf16rn(t[cw + j][iw]);
#pragma unroll
  for (int j = 0; j < 8; ++j) p1[j] = bf16rn(t[cw + 8 + j][iw]);
  *(us8*)dst = p0;
  *(us8*)(dst + 8) = p1;
}

// ---------------- QKV projection GEMM ----------------
// A[b][i][c] x wcat[o][c]^T -> q[b][i][d], k[b][i][d], vT[b][c][j=i]
__global__ __launch_bounds__(256) void proj_gemm(
    const unsigned short* __restrict__ A, const unsigned short* __restrict__ wcat,
    const float* __restrict__ bcat,
    unsigned short* __restrict__ qo, unsigned short* __restrict__ ko,
    unsigned short* __restrict__ vto) {
  __shared__ unsigned short sA[4096], sB[4096];
  const int b = blockIdx.z, m0 = blockIdx.x * 128, n0 = blockIdx.y * 128;
  const int tid = threadIdx.x, wave = tid >> 6, lane = tid & 63;
  f32x4 acc[4][4];
#pragma unroll
  for (int i = 0; i < 4; ++i)
#pragma unroll
    for (int j = 0; j < 4; ++j) acc[i][j] = (f32x4)(0.0f);

  gemm_core<512>(A + (size_t)b * NN * CC, wcat, m0, n0, tid, sA, sB, acc);

  const int wm = (wave & 1) * 64, wn = (wave >> 1) * 64;
#pragma unroll
  for (int i = 0; i < 4; ++i)
#pragma unroll
    for (int j = 0; j < 4; ++j) {
      int col  = n0 + wn + j * 16 + (lane & 15);
      int rowb = m0 + wm + i * 16 + (lane >> 4) * 4;
      float bias = bcat[col];
      if (col < 64) {
#pragma unroll
        for (int r = 0; r < 4; ++r)
          qo[((size_t)b * NN + rowb + r) * DD + col] = bf16rn(acc[i][j][r] + bias);
      } else if (col < 128) {
#pragma unroll
        for (int r = 0; r < 4; ++r)
          ko[((size_t)b * NN + rowb + r) * DD + col - 64] = bf16rn(acc[i][j][r] + bias);
      } else {
        int c = col - 128;
        us4 pk;
#pragma unroll
        for (int r = 0; r < 4; ++r) pk[r] = bf16rn(acc[i][j][r] + bias);
        *(us4*)(vto + ((size_t)b * CC + c) * NN + rowb) = pk;   // vT: 4 contiguous j
      }
    }
}

// ---------------- scores GEMM: q x k^T -> scores fp32 [b'][i][j] (group-local) ----------------
__global__ __launch_bounds__(256) void scores_gemm(
    const unsigned short* __restrict__ q, const unsigned short* __restrict__ k,
    float* __restrict__ scores) {
  __shared__ unsigned short sA[4096], sB[4096];
  const int b = blockIdx.z, m0 = blockIdx.x * 128, n0 = blockIdx.y * 128;
  const int tid = threadIdx.x, wave = tid >> 6, lane = tid & 63;
  f32x4 acc[4][4];
#pragma unroll
  for (int i = 0; i < 4; ++i)
#pragma unroll
    for (int j = 0; j < 4; ++j) acc[i][j] = (f32x4)(0.0f);

  gemm_core<64>(q + (size_t)b * NN * DD, k + (size_t)b * NN * DD, m0, n0, tid, sA, sB, acc);

  const int wm = (wave & 1) * 64, wn = (wave >> 1) * 64;
#pragma unroll
  for (int i = 0; i < 4; ++i)
#pragma unroll
    for (int j = 0; j < 4; ++j) {
      int col  = n0 + wn + j * 16 + (lane & 15);
      int rowb = m0 + wm + i * 16 + (lane >> 4) * 4;
#pragma unroll
      for (int r = 0; r < 4; ++r)
        scores[((size_t)b * NN + rowb + r) * NN + col] = acc[i][j][r];
    }
}

// ---------------- softmax: one wave per row, scores fp32 -> P bf16 (packed) ----------------
__global__ __launch_bounds__(256) void softmax_kernel(const float* __restrict__ scores,
                                                      unsigned short* __restrict__ P) {
  const int wave = threadIdx.x >> 6, lane = threadIdx.x & 63;
  const size_t row = (size_t)blockIdx.x * 4 + wave;
  const float* s = scores + row * NN;
  f4 v[4];
  float m = -1e30f;
#pragma unroll
  for (int t = 0; t < 4; ++t) {
    v[t] = *(const f4*)(s + t * 256 + lane * 4);
    m = fmaxf(m, fmaxf(fmaxf(v[t].x, v[t].y), fmaxf(v[t].z, v[t].w)));
  }
#pragma unroll
  for (int off = 32; off > 0; off >>= 1) m = fmaxf(m, __shfl_xor(m, off, 64));
  float sum = 0.f;
#pragma unroll
  for (int t = 0; t < 4; ++t) {
    v[t].x = __expf(v[t].x - m); v[t].y = __expf(v[t].y - m);
    v[t].z = __expf(v[t].z - m); v[t].w = __expf(v[t].w - m);
    sum += v[t].x + v[t].y + v[t].z + v[t].w;
  }
#pragma unroll
  for (int off = 32; off > 0; off >>= 1) sum += __shfl_xor(sum, off, 64);
  float inv = 1.0f / sum;
#pragma unroll
  for (int t = 0; t < 4; ++t) {
    us4 pk;
    pk[0] = bf16rn(v[t].x * inv); pk[1] = bf16rn(v[t].y * inv);
    pk[2] = bf16rn(v[t].z * inv); pk[3] = bf16rn(v[t].w * inv);
    *(us4*)(P + row * NN + t * 256 + lane * 4) = pk;
  }
}

// ---------------- PV GEMM: P[b'] x vT[b']^T -> attnout bf16 [b'][i][c] (group-local) ----------------
__global__ __launch_bounds__(256) void pv_gemm(
    const unsigned short* __restrict__ P, const unsigned short* __restrict__ vT,
    unsigned short* __restrict__ attnout) {
  __shared__ unsigned short sA[4096], sB[4096];
  const int b = blockIdx.z, m0 = blockIdx.x * 128, n0 = blockIdx.y * 128;
  const int tid = threadIdx.x, wave = tid >> 6, lane = tid & 63;
  f32x4 acc[4][4];
#pragma unroll
  for (int i = 0; i < 4; ++i)
#pragma unroll
    for (int j = 0; j < 4; ++j) acc[i][j] = (f32x4)(0.0f);

  gemm_core<1024>(P + (size_t)b * NN * NN, vT + (size_t)b * CC * NN, m0, n0, tid, sA, sB, acc);

  const int wm = (wave & 1) * 64, wn = (wave >> 1) * 64;
#pragma unroll
  for (int i = 0; i < 4; ++i)
#pragma unroll
    for (int j = 0; j < 4; ++j) {
      int col  = n0 + wn + j * 16 + (lane & 15);
      int rowb = m0 + wm + i * 16 + (lane >> 4) * 4;
#pragma unroll
      for (int r = 0; r < 4; ++r)
        attnout[((size_t)b * NN + rowb + r) * CC + col] = bf16rn(acc[i][j][r]);
    }
}

// ---------------- output projection: ow[co][c] x attnout[i][c]^T -> out[b][co][i] ----------------
__global__ __launch_bounds__(256) void outproj_gemm(
    const unsigned short* __restrict__ owb, const unsigned short* __restrict__ attnout,
    const float* __restrict__ ob, float* __restrict__ out) {
  __shared__ unsigned short sA[4096], sB[4096];
  const int b = blockIdx.z, m0 = blockIdx.x * 128, n0 = blockIdx.y * 128;
  const int tid = threadIdx.x, wave = tid >> 6, lane = tid & 63;
  f32x4 acc[4][4];
#pragma unroll
  for (int i = 0; i < 4; ++i)
#pragma unroll
    for (int j = 0; j < 4; ++j) acc[i][j] = (f32x4)(0.0f);

  gemm_core<512>(owb, attnout + (size_t)b * NN * CC, m0, n0, tid, sA, sB, acc);

  const int wm = (wave & 1) * 64, wn = (wave >> 1) * 64;
#pragma unroll
  for (int i = 0; i < 4; ++i)
#pragma unroll
    for (int j = 0; j < 4; ++j) {
      int col  = n0 + wn + j * 16 + (lane & 15);      // i
      int rowb = m0 + wm + i * 16 + (lane >> 4) * 4;  // co
      f4 b4 = *(const f4*)(ob + rowb);
#pragma unroll
      for (int r = 0; r < 4; ++r)
        out[((size_t)b * CC + rowb + r) * NN + col] = acc[i][j][r] + ((const float*)&b4)[r];
    }
}

extern "C" void kernel_launch(void* const* d_in, const int* in_sizes, int n_in,
                              void* d_out, int out_size, void* d_ws, size_t ws_size,
                              hipStream_t stream) {
  const float* x   = (const float*)d_in[0];
  const float* pos = (const float*)d_in[1];
  const float* qw  = (const float*)d_in[2];
  const float* qb  = (const float*)d_in[3];
  const float* kw  = (const float*)d_in[4];
  const float* kb  = (const float*)d_in[5];
  const float* vw  = (const float*)d_in[6];
  const float* vb  = (const float*)d_in[7];
  const float* ow  = (const float*)d_in[8];
  const float* ob  = (const float*)d_in[9];
  float* out = (float*)d_out;

  // workspace layout (bytes), total ~121.1 MB:
  char* w = (char*)d_ws;
  unsigned short* wcat = (unsigned short*)w; w += (size_t)640 * 512 * 2;        // 0.66 MB
  unsigned short* owb  = (unsigned short*)w; w += (size_t)512 * 512 * 2;        // 0.52 MB
  float*          bcat = (float*)w;          w += 640 * 4;                      // 2.5 KB
  unsigned short* A    = (unsigned short*)w; w += (size_t)BB * NN * CC * 2;     // 32 MB (reused as attnout)
  unsigned short* q    = (unsigned short*)w; w += (size_t)BB * NN * DD * 2;     // 4 MB
  unsigned short* k    = (unsigned short*)w; w += (size_t)BB * NN * DD * 2;     // 4 MB
  unsigned short* vT   = (unsigned short*)w; w += (size_t)BB * CC * NN * 2;     // 32 MB
  float*       scoresG = (float*)w;          w += (size_t)GRP * NN * NN * 4;    // 32 MB (per-group, reused)
  unsigned short* PG   = (unsigned short*)w; w += (size_t)GRP * NN * NN * 2;    // 16 MB (per-group, reused)
  unsigned short* attnout = A;  // A is dead after proj_gemm

  hipLaunchKernelGGL(prep_w, dim3(2304), dim3(256), 0, stream,
                     qw, kw, vw, qb, kb, vb, ow, wcat, owb, bcat);
  hipLaunchKernelGGL(prep_x, dim3(16, 8, 32), dim3(256), 0, stream, x, pos, A);
  hipLaunchKernelGGL(proj_gemm, dim3(8, 5, 32), dim3(256), 0, stream,
                     A, wcat, bcat, q, k, vT);

  for (int g = 0; g < NGRP; ++g) {
    const unsigned short* qg  = q  + (size_t)g * GRP * NN * DD;
    const unsigned short* kg  = k  + (size_t)g * GRP * NN * DD;
    const unsigned short* vTg = vT + (size_t)g * GRP * CC * NN;
    unsigned short* aog = attnout + (size_t)g * GRP * NN * CC;
    hipLaunchKernelGGL(scores_gemm, dim3(8, 8, GRP), dim3(256), 0, stream, qg, kg, scoresG);
    hipLaunchKernelGGL(softmax_kernel, dim3(GRP * NN / 4), dim3(256), 0, stream, scoresG, PG);
    hipLaunchKernelGGL(pv_gemm, dim3(8, 4, GRP), dim3(256), 0, stream, PG, vTg, aog);
  }

  hipLaunchKernelGGL(outproj_gemm, dim3(4, 8, 32), dim3(256), 0, stream,
                     owb, attnout, ob, out);
}

// Round 4
// 377.754 us; speedup vs baseline: 7.3282x; 1.0120x over previous
//
#include <hip/hip_runtime.h>

// SpatialAttention: B=32, C=512, D=64, N=1024 (H=W=32)
#define BB 32
#define CC 512
#define DD 64
#define NN 1024
#define GRP 8                 // batches per attention group
#define NGRP (BB / GRP)       // 4 groups

typedef float4 f4;
typedef __attribute__((ext_vector_type(8))) short bf16x8;     // 8 bf16 = 4 VGPRs (MFMA A/B frag)
typedef __attribute__((ext_vector_type(4))) float f32x4;      // MFMA C/D frag
typedef __attribute__((ext_vector_type(4))) unsigned short us4;
typedef __attribute__((ext_vector_type(8))) unsigned short us8;

__device__ inline unsigned short bf16rn(float f) {
  union { float f; unsigned u; } v; v.f = f;
  unsigned r = v.u + 0x7fff + ((v.u >> 16) & 1);   // round-to-nearest-even
  return (unsigned short)(r >> 16);
}

__device__ inline void gl_lds16(const void* g, void* l) {
  // async global->LDS, 16B/lane; LDS dest = wave-uniform base + lane*16
  __builtin_amdgcn_global_load_lds(
      (const __attribute__((address_space(1))) unsigned int*)g,
      (__attribute__((address_space(3))) unsigned int*)l, 16, 0, 0);
}

// ---- shared GEMM core: C[128m x 128n] += A[M][K] * Bt[N][K]^T, bf16, BK=64 ----
// LDS tiles: 128 rows x 64 k-elems (128 B = 32 banks per row), XOR-swizzled:
// slot s of row r holds global k-group (s ^ (r&7)); 16B groups.
// Staging: one global_load_lds covers 8 rows (64 lanes x 16B); lane reads global
// group (lane&7)^(lane>>3) so LDS dest stays lane-contiguous. Fragment reads at
// slot ((ks*4+kq) ^ (fm&7)) touch all 32 banks exactly twice per 16-lane phase
// (2-way = free, m136) -> conflict-free at throughput floor.
template <int KDIM>
__device__ inline void gemm_core(const unsigned short* __restrict__ A,
                                 const unsigned short* __restrict__ Bt,
                                 int m0, int n0, int tid,
                                 unsigned short* sA, unsigned short* sB,
                                 f32x4 acc[4][4]) {
  const int wave = tid >> 6, lane = tid & 63;
  const int wm = (wave & 1) * 64, wn = (wave >> 1) * 64;
  const int fm = lane & 15;           // fragment row (m or n)
  const int kq = lane >> 4;           // fragment k-group (0..3) within 32-k window
  const int srow = lane >> 3;         // staging: row within 8-row slab (0..7)
  const int sg   = (lane & 7) ^ srow; // staging: global k-group (swizzled)

  for (int k0 = 0; k0 < KDIM; k0 += 64) {
#pragma unroll
    for (int t = 0; t < 4; ++t) {
      const int R = wave * 32 + t * 8;     // row base of this 8-row slab
      gl_lds16(A  + (size_t)(m0 + R + srow) * KDIM + k0 + sg * 8, sA + R * 64);
      gl_lds16(Bt + (size_t)(n0 + R + srow) * KDIM + k0 + sg * 8, sB + R * 64);
    }
    __syncthreads();   // drains vmcnt (global_load_lds) for all waves
#pragma unroll
    for (int ks = 0; ks < 2; ++ks) {
      bf16x8 af[4], bfr[4];
#pragma unroll
      for (int i = 0; i < 4; ++i) {
        const int ra = wm + i * 16 + fm;
        const int rb = wn + i * 16 + fm;
        af[i]  = *(const bf16x8*)(sA + ra * 64 + ((ks * 4 + kq) ^ (ra & 7)) * 8);
        bfr[i] = *(const bf16x8*)(sB + rb * 64 + ((ks * 4 + kq) ^ (rb & 7)) * 8);
      }
#pragma unroll
      for (int i = 0; i < 4; ++i)
#pragma unroll
        for (int j = 0; j < 4; ++j)
          acc[i][j] = __builtin_amdgcn_mfma_f32_16x16x32_bf16(af[i], bfr[j], acc[i][j], 0, 0, 0);
    }
    __syncthreads();
  }
}

// ---------------- prep: weights -> bf16 ----------------
__global__ __launch_bounds__(256) void prep_w(
    const float* __restrict__ qw, const float* __restrict__ kw, const float* __restrict__ vw,
    const float* __restrict__ qb, const float* __restrict__ kb, const float* __restrict__ vb,
    const float* __restrict__ ow,
    unsigned short* __restrict__ wcat, unsigned short* __restrict__ owb,
    float* __restrict__ bcat) {
  int idx = blockIdx.x * 256 + threadIdx.x;   // 0 .. 640*512 + 512*512 - 1
  if (idx < 640 * 512) {
    int row = idx >> 9;
    float v = (row < 64) ? qw[idx] : (row < 128) ? kw[idx - 64 * 512] : vw[idx - 128 * 512];
    wcat[idx] = bf16rn(v);
    if (idx < 640) bcat[idx] = (idx < 64) ? qb[idx] : (idx < 128) ? kb[idx - 64] : vb[idx - 128];
  } else {
    int j = idx - 640 * 512;
    owb[j] = bf16rn(ow[j]);
  }
}

// ---------------- prep: A[b][i][c] = bf16(x[b][c][i] + pos[c][i]) ----------------
__global__ __launch_bounds__(256) void prep_x(const float* __restrict__ x,
                                              const float* __restrict__ pos,
                                              unsigned short* __restrict__ A) {
  __shared__ float t[64][65];
  const int b = blockIdx.z, i0 = blockIdx.x * 64, c0 = blockIdx.y * 64;
  const int tid = threadIdx.x;
  const int ci = tid >> 4, il = (tid & 15) * 4;
  const float* xb = x + (size_t)b * CC * NN;
#pragma unroll
  for (int r = 0; r < 4; ++r) {
    int cl = r * 16 + ci;
    f4 xv = *(const f4*)(xb  + (size_t)(c0 + cl) * NN + i0 + il);
    f4 pv = *(const f4*)(pos + (size_t)(c0 + cl) * NN + i0 + il);
    t[cl][il + 0] = xv.x + pv.x;
    t[cl][il + 1] = xv.y + pv.y;
    t[cl][il + 2] = xv.z + pv.z;
    t[cl][il + 3] = xv.w + pv.w;
  }
  __syncthreads();
  const int iw = tid >> 2, cw = (tid & 3) * 16;
  unsigned short* dst = A + ((size_t)b * NN + i0 + iw) * CC + c0 + cw;
  us8 p0, p1;
#pragma unroll
  for (int j = 0; j < 8; ++j) p0[j] = bf16rn(t[cw + j][iw]);
#pragma unroll
  for (int j = 0; j < 8; ++j) p1[j] = bf16rn(t[cw + 8 + j][iw]);
  *(us8*)dst = p0;
  *(us8*)(dst + 8) = p1;
}

// ---------------- QKV projection GEMM ----------------
// A[b][i][c] x wcat[o][c]^T -> q[b][i][d], k[b][i][d], vT[b][c][j=i]
__global__ __launch_bounds__(256) void proj_gemm(
    const unsigned short* __restrict__ A, const unsigned short* __restrict__ wcat,
    const float* __restrict__ bcat,
    unsigned short* __restrict__ qo, unsigned short* __restrict__ ko,
    unsigned short* __restrict__ vto) {
  __shared__ unsigned short sA[8192], sB[8192];
  const int b = blockIdx.z, m0 = blockIdx.x * 128, n0 = blockIdx.y * 128;
  const int tid = threadIdx.x, wave = tid >> 6, lane = tid & 63;
  f32x4 acc[4][4];
#pragma unroll
  for (int i = 0; i < 4; ++i)
#pragma unroll
    for (int j = 0; j < 4; ++j) acc[i][j] = (f32x4)(0.0f);

  gemm_core<512>(A + (size_t)b * NN * CC, wcat, m0, n0, tid, sA, sB, acc);

  const int wm = (wave & 1) * 64, wn = (wave >> 1) * 64;
#pragma unroll
  for (int i = 0; i < 4; ++i)
#pragma unroll
    for (int j = 0; j < 4; ++j) {
      int col  = n0 + wn + j * 16 + (lane & 15);
      int rowb = m0 + wm + i * 16 + (lane >> 4) * 4;
      float bias = bcat[col];
      if (col < 64) {
#pragma unroll
        for (int r = 0; r < 4; ++r)
          qo[((size_t)b * NN + rowb + r) * DD + col] = bf16rn(acc[i][j][r] + bias);
      } else if (col < 128) {
#pragma unroll
        for (int r = 0; r < 4; ++r)
          ko[((size_t)b * NN + rowb + r) * DD + col - 64] = bf16rn(acc[i][j][r] + bias);
      } else {
        int c = col - 128;
        us4 pk;
#pragma unroll
        for (int r = 0; r < 4; ++r) pk[r] = bf16rn(acc[i][j][r] + bias);
        *(us4*)(vto + ((size_t)b * CC + c) * NN + rowb) = pk;   // vT: 4 contiguous j
      }
    }
}

// ---------------- scores GEMM: q x k^T -> scores fp32 [b'][i][j] (group-local) ----------------
__global__ __launch_bounds__(256) void scores_gemm(
    const unsigned short* __restrict__ q, const unsigned short* __restrict__ k,
    float* __restrict__ scores) {
  __shared__ unsigned short sA[8192], sB[8192];
  const int b = blockIdx.z, m0 = blockIdx.x * 128, n0 = blockIdx.y * 128;
  const int tid = threadIdx.x, wave = tid >> 6, lane = tid & 63;
  f32x4 acc[4][4];
#pragma unroll
  for (int i = 0; i < 4; ++i)
#pragma unroll
    for (int j = 0; j < 4; ++j) acc[i][j] = (f32x4)(0.0f);

  gemm_core<64>(q + (size_t)b * NN * DD, k + (size_t)b * NN * DD, m0, n0, tid, sA, sB, acc);

  const int wm = (wave & 1) * 64, wn = (wave >> 1) * 64;
#pragma unroll
  for (int i = 0; i < 4; ++i)
#pragma unroll
    for (int j = 0; j < 4; ++j) {
      int col  = n0 + wn + j * 16 + (lane & 15);
      int rowb = m0 + wm + i * 16 + (lane >> 4) * 4;
#pragma unroll
      for (int r = 0; r < 4; ++r)
        scores[((size_t)b * NN + rowb + r) * NN + col] = acc[i][j][r];
    }
}

// ---------------- softmax: one wave per row, scores fp32 -> P bf16 (packed) ----------------
__global__ __launch_bounds__(256) void softmax_kernel(const float* __restrict__ scores,
                                                      unsigned short* __restrict__ P) {
  const int wave = threadIdx.x >> 6, lane = threadIdx.x & 63;
  const size_t row = (size_t)blockIdx.x * 4 + wave;
  const float* s = scores + row * NN;
  f4 v[4];
  float m = -1e30f;
#pragma unroll
  for (int t = 0; t < 4; ++t) {
    v[t] = *(const f4*)(s + t * 256 + lane * 4);
    m = fmaxf(m, fmaxf(fmaxf(v[t].x, v[t].y), fmaxf(v[t].z, v[t].w)));
  }
#pragma unroll
  for (int off = 32; off > 0; off >>= 1) m = fmaxf(m, __shfl_xor(m, off, 64));
  float sum = 0.f;
#pragma unroll
  for (int t = 0; t < 4; ++t) {
    v[t].x = __expf(v[t].x - m); v[t].y = __expf(v[t].y - m);
    v[t].z = __expf(v[t].z - m); v[t].w = __expf(v[t].w - m);
    sum += v[t].x + v[t].y + v[t].z + v[t].w;
  }
#pragma unroll
  for (int off = 32; off > 0; off >>= 1) sum += __shfl_xor(sum, off, 64);
  float inv = 1.0f / sum;
#pragma unroll
  for (int t = 0; t < 4; ++t) {
    us4 pk;
    pk[0] = bf16rn(v[t].x * inv); pk[1] = bf16rn(v[t].y * inv);
    pk[2] = bf16rn(v[t].z * inv); pk[3] = bf16rn(v[t].w * inv);
    *(us4*)(P + row * NN + t * 256 + lane * 4) = pk;
  }
}

// ---------------- PV GEMM: P[b'] x vT[b']^T -> attnout bf16 [b'][i][c] (group-local) ----------------
__global__ __launch_bounds__(256) void pv_gemm(
    const unsigned short* __restrict__ P, const unsigned short* __restrict__ vT,
    unsigned short* __restrict__ attnout) {
  __shared__ unsigned short sA[8192], sB[8192];
  const int b = blockIdx.z, m0 = blockIdx.x * 128, n0 = blockIdx.y * 128;
  const int tid = threadIdx.x, wave = tid >> 6, lane = tid & 63;
  f32x4 acc[4][4];
#pragma unroll
  for (int i = 0; i < 4; ++i)
#pragma unroll
    for (int j = 0; j < 4; ++j) acc[i][j] = (f32x4)(0.0f);

  gemm_core<1024>(P + (size_t)b * NN * NN, vT + (size_t)b * CC * NN, m0, n0, tid, sA, sB, acc);

  const int wm = (wave & 1) * 64, wn = (wave >> 1) * 64;
#pragma unroll
  for (int i = 0; i < 4; ++i)
#pragma unroll
    for (int j = 0; j < 4; ++j) {
      int col  = n0 + wn + j * 16 + (lane & 15);
      int rowb = m0 + wm + i * 16 + (lane >> 4) * 4;
#pragma unroll
      for (int r = 0; r < 4; ++r)
        attnout[((size_t)b * NN + rowb + r) * CC + col] = bf16rn(acc[i][j][r]);
    }
}

// ---------------- output projection: ow[co][c] x attnout[i][c]^T -> out[b][co][i] ----------------
__global__ __launch_bounds__(256) void outproj_gemm(
    const unsigned short* __restrict__ owb, const unsigned short* __restrict__ attnout,
    const float* __restrict__ ob, float* __restrict__ out) {
  __shared__ unsigned short sA[8192], sB[8192];
  const int b = blockIdx.z, m0 = blockIdx.x * 128, n0 = blockIdx.y * 128;
  const int tid = threadIdx.x, wave = tid >> 6, lane = tid & 63;
  f32x4 acc[4][4];
#pragma unroll
  for (int i = 0; i < 4; ++i)
#pragma unroll
    for (int j = 0; j < 4; ++j) acc[i][j] = (f32x4)(0.0f);

  gemm_core<512>(owb, attnout + (size_t)b * NN * CC, m0, n0, tid, sA, sB, acc);

  const int wm = (wave & 1) * 64, wn = (wave >> 1) * 64;
#pragma unroll
  for (int i = 0; i < 4; ++i)
#pragma unroll
    for (int j = 0; j < 4; ++j) {
      int col  = n0 + wn + j * 16 + (lane & 15);      // i
      int rowb = m0 + wm + i * 16 + (lane >> 4) * 4;  // co
      f4 b4 = *(const f4*)(ob + rowb);
#pragma unroll
      for (int r = 0; r < 4; ++r)
        out[((size_t)b * CC + rowb + r) * NN + col] = acc[i][j][r] + ((const float*)&b4)[r];
    }
}

extern "C" void kernel_launch(void* const* d_in, const int* in_sizes, int n_in,
                              void* d_out, int out_size, void* d_ws, size_t ws_size,
                              hipStream_t stream) {
  const float* x   = (const float*)d_in[0];
  const float* pos = (const float*)d_in[1];
  const float* qw  = (const float*)d_in[2];
  const float* qb  = (const float*)d_in[3];
  const float* kw  = (const float*)d_in[4];
  const float* kb  = (const float*)d_in[5];
  const float* vw  = (const float*)d_in[6];
  const float* vb  = (const float*)d_in[7];
  const float* ow  = (const float*)d_in[8];
  const float* ob  = (const float*)d_in[9];
  float* out = (float*)d_out;

  // workspace layout (bytes), total ~121.1 MB:
  char* w = (char*)d_ws;
  unsigned short* wcat = (unsigned short*)w; w += (size_t)640 * 512 * 2;        // 0.66 MB
  unsigned short* owb  = (unsigned short*)w; w += (size_t)512 * 512 * 2;        // 0.52 MB
  float*          bcat = (float*)w;          w += 640 * 4;                      // 2.5 KB
  unsigned short* A    = (unsigned short*)w; w += (size_t)BB * NN * CC * 2;     // 32 MB (reused as attnout)
  unsigned short* q    = (unsigned short*)w; w += (size_t)BB * NN * DD * 2;     // 4 MB
  unsigned short* k    = (unsigned short*)w; w += (size_t)BB * NN * DD * 2;     // 4 MB
  unsigned short* vT   = (unsigned short*)w; w += (size_t)BB * CC * NN * 2;     // 32 MB
  float*       scoresG = (float*)w;          w += (size_t)GRP * NN * NN * 4;    // 32 MB (per-group, reused)
  unsigned short* PG   = (unsigned short*)w; w += (size_t)GRP * NN * NN * 2;    // 16 MB (per-group, reused)
  unsigned short* attnout = A;  // A is dead after proj_gemm

  hipLaunchKernelGGL(prep_w, dim3(2304), dim3(256), 0, stream,
                     qw, kw, vw, qb, kb, vb, ow, wcat, owb, bcat);
  hipLaunchKernelGGL(prep_x, dim3(16, 8, 32), dim3(256), 0, stream, x, pos, A);
  hipLaunchKernelGGL(proj_gemm, dim3(8, 5, 32), dim3(256), 0, stream,
                     A, wcat, bcat, q, k, vT);

  for (int g = 0; g < NGRP; ++g) {
    const unsigned short* qg  = q  + (size_t)g * GRP * NN * DD;
    const unsigned short* kg  = k  + (size_t)g * GRP * NN * DD;
    const unsigned short* vTg = vT + (size_t)g * GRP * CC * NN;
    unsigned short* aog = attnout + (size_t)g * GRP * NN * CC;
    hipLaunchKernelGGL(scores_gemm, dim3(8, 8, GRP), dim3(256), 0, stream, qg, kg, scoresG);
    hipLaunchKernelGGL(softmax_kernel, dim3(GRP * NN / 4), dim3(256), 0, stream, scoresG, PG);
    hipLaunchKernelGGL(pv_gemm, dim3(8, 4, GRP), dim3(256), 0, stream, PG, vTg, aog);
  }

  hipLaunchKernelGGL(outproj_gemm, dim3(4, 8, 32), dim3(256), 0, stream,
                     owb, attnout, ob, out);
}